// Round 12
// baseline (117.538 us; speedup 1.0000x reference)
//
#include <hip/hip_runtime.h>
#include <hip/hip_bf16.h>

// Fused map-obs attention (Attention_5815385719367), MI355X/gfx950.
// R12: raise arithmetic intensity per staged K/V fragment — each wave owns
// TWO q-tiles (block = 4 waves = 256 q-rows). Per key-block the wave runs
// both tiles tile-at-a-time (s/p registers die between tiles; peak regs
// ~115 <= 128 so 4 waves/SIMD holds). LDS read traffic and per-q L2 K/V
// traffic halve; VALU total unchanged. ks=16 -> grid 64*16 = 1024 blocks =
// 4 blocks/CU. Partials bf16.
//
// ws layout (~23 MB):
//   qbf  [n_map][64] bf16 (pre-scaled by IT)
//   Kp   [n_obs/32][4][64][8] bf16    (packed K fragments, 4KB/kb)
//   Vp   [n_obs/32][2][64][8] bf16    (packed V^T fragments, 2KB/kb)
//   self_score[n_map] f32, gated_map[n_map][32] f32
//   oP [ks][ntiles][32][32] bf16,  lP [ks][n_map] f32

typedef float f32x16 __attribute__((ext_vector_type(16)));
typedef short bf16x8 __attribute__((ext_vector_type(8)));
typedef unsigned int u32;

__device__ __forceinline__ u32 cvt_pk_bf16(float lo, float hi) {
    u32 r;
    asm("v_cvt_pk_bf16_f32 %0, %1, %2" : "=v"(r) : "v"(lo), "v"(hi));
    return r;
}
__device__ __forceinline__ void permswap32(u32& a, u32& b) {
    asm("v_permlane32_swap_b32 %0, %1" : "+v"(a), "+v"(b));
}

#define IT 0.18033688011112042f  // log2(e)/TEMPERATURE, T=8
#define LOG2E 1.44269504089f

// ---------------------------------------------------------------- prep ----
// 256 thr = 4 waves; wave handles 8 rows (32 rows/block), d-loop outer.
__global__ __launch_bounds__(256) void prep_kernel(
    const float* __restrict__ map_code, const float* __restrict__ obs_code,
    const float* __restrict__ Wq, const float* __restrict__ Wk,
    const float* __restrict__ Wv,
    __hip_bfloat16* __restrict__ qbf, __hip_bfloat16* __restrict__ Kp,
    __hip_bfloat16* __restrict__ Vp, float* __restrict__ self_score,
    float* __restrict__ gated_map, int n_map, int n_obs)
{
    __shared__ float xs[32 * 64];
    const int t = threadIdx.x;
    const int w = t >> 6;
    const int e = t & 63;
    const int r0 = blockIdx.x * 32;
    const int total = n_map + n_obs;

    // stage 32 rows of concat(map, obs), coalesced
    #pragma unroll
    for (int i = 0; i < 8; ++i) {
        const int idx = i * 256 + t;
        const int gr = r0 + (idx >> 6);
        const int col = idx & 63;
        float val = 0.0f;
        if (gr < n_map)      val = map_code[(size_t)gr * 64 + col];
        else if (gr < total) val = obs_code[(size_t)(gr - n_map) * 64 + col];
        xs[idx] = val;
    }
    __syncthreads();

    float qa[8] = {}, ka[8] = {}, va[8] = {};
    const float* xw = xs + (w * 8) * 64;
    #pragma unroll 4
    for (int d = 0; d < 64; ++d) {
        const float wq = Wq[d * 64 + e];
        const float wk = Wk[d * 64 + e];
        const float wv = Wv[d * 64 + e];
        #pragma unroll
        for (int i = 0; i < 8; ++i) {
            const float x = xw[i * 64 + d];   // LDS broadcast
            qa[i] = fmaf(x, wq, qa[i]);
            ka[i] = fmaf(x, wk, ka[i]);
            va[i] = fmaf(x, wv, va[i]);
        }
    }

    #pragma unroll
    for (int i = 0; i < 8; ++i) {
        const int r = r0 + w * 8 + i;
        if (r >= total) break;
        const bool is_map = r < n_map;
        // GLU: lanes 0..31 hold a=v[e], need b=v[e+32]
        const float vother = __shfl_xor(va[i], 32);
        const float sig = 1.0f / (1.0f + __builtin_amdgcn_exp2f(-vother * LOG2E));
        const float g = va[i] * sig; // valid for lanes e < 32

        if (is_map) {
            qbf[(size_t)r * 64 + e] = __float2bfloat16(qa[i] * IT);
            float qk = qa[i] * ka[i];
            #pragma unroll
            for (int off = 32; off; off >>= 1) qk += __shfl_xor(qk, off);
            if (e == 0) self_score[r] = qk;
            if (e < 32) gated_map[(size_t)r * 32 + e] = g;
        } else {
            const int j  = r - n_map;          // key index
            const int kb = j >> 5, jq = j & 31;
            {   // Kp: thread e holds K[j][d=e]
                const int c = e >> 4, h2 = (e >> 3) & 1, ii = e & 7;
                Kp[(size_t)kb * 2048 + c * 512 + (h2 * 32 + jq) * 8 + ii] =
                    __float2bfloat16(ka[i]);
            }
            if (e < 32) {  // Vp: thread e holds gated[key=j][vdim=e]
                const int h = jq >> 4, h3 = (jq >> 3) & 1, ii = jq & 7;
                Vp[(size_t)kb * 1024 + h * 512 + (h3 * 32 + e) * 8 + ii] =
                    __float2bfloat16(g);
            }
        }
    }
}

// -------------------------------------------------------------- attn ------
// grid = (n_map/256) * ks. Block: qb = bid>>kslog (8 q-tiles = 256 q-rows),
// slice = bid & (ks-1). Wave w owns q-tiles qb*8+w and qb*8+w+4 (two full
// softmax states; tile-at-a-time per key-block to cap live registers).
// K/V staged in LDS once per block, double-buffered in 2-kb rounds.
// Swapped QK^T (Q pre-scaled by IT), O^T orientation, no-max softmax.
#define WAVES 4
__global__ __launch_bounds__(64 * WAVES, 4) void attn_partial(
    const __hip_bfloat16* __restrict__ qbf, const __hip_bfloat16* __restrict__ Kp,
    const __hip_bfloat16* __restrict__ Vp,
    __hip_bfloat16* __restrict__ oP, float* __restrict__ lP,
    int n_obs, int n_map, int kslog)
{
    const int tid  = threadIdx.x;
    const int w    = tid >> 6;
    const int lane = tid & 63;
    const int ql   = lane & 31;
    const int hi   = lane >> 5;
    const int ks   = 1 << kslog;
    const int qb   = blockIdx.x >> kslog;
    const int slice= blockIdx.x & (ks - 1);
    const int tile1= qb * 8 + w;               // global q-tile indices
    const int tile2= tile1 + 4;
    const int q1   = tile1 * 32 + ql;
    const int q2   = tile2 * 32 + ql;

    // double-buffered K/V pair staging: [2] x (K 8KB | V 4KB)
    __shared__ __align__(16) char kv[2][12288];

    // Q fragments for both tiles
    bf16x8 qf1[4], qf2[4];
    {
        const __hip_bfloat16* qrow1 = qbf + (size_t)q1 * 64 + 8 * hi;
        const __hip_bfloat16* qrow2 = qbf + (size_t)q2 * 64 + 8 * hi;
        #pragma unroll
        for (int c = 0; c < 4; ++c) {
            qf1[c] = *reinterpret_cast<const bf16x8*>(qrow1 + c * 16);
            qf2[c] = *reinterpret_cast<const bf16x8*>(qrow2 + c * 16);
        }
    }

    float l1A = 0.0f, l1B = 0.0f, l2A = 0.0f, l2B = 0.0f;
    f32x16 o1 = {}, o2 = {};

    const int nkb      = (n_obs >> kslog) >> 5;   // key-blocks per slice
    const int kb_begin = slice * nkb;
    const int npairs   = nkb >> 1;
    const char* Kb = (const char*)Kp;
    const char* Vb = (const char*)Vp;

    uint4 gK0, gK1, gV;
    auto gloadPair = [&](int kb0) {   // stage kbs (kb0, kb0+1) -> regs
        const char* ksrc = Kb + (size_t)kb0 * 4096 + tid * 32;
        gK0 = *reinterpret_cast<const uint4*>(ksrc);
        gK1 = *reinterpret_cast<const uint4*>(ksrc + 16);
        gV  = *reinterpret_cast<const uint4*>(Vb + (size_t)kb0 * 2048 + tid * 16);
    };
    auto swritePair = [&](char* buf) {
        *reinterpret_cast<uint4*>(buf + tid * 32)        = gK0;
        *reinterpret_cast<uint4*>(buf + tid * 32 + 16)   = gK1;
        *reinterpret_cast<uint4*>(buf + 8192 + tid * 16) = gV;
    };
    auto readsub = [&](const char* buf, int j, bf16x8 (&kf)[4], bf16x8 (&vf)[2]) {
        const char* kbp = buf + j * 4096 + lane * 16;
        #pragma unroll
        for (int c = 0; c < 4; ++c)
            kf[c] = *reinterpret_cast<const bf16x8*>(kbp + c * 1024);
        const char* vbp = buf + 8192 + j * 2048 + lane * 16;
        vf[0] = *reinterpret_cast<const bf16x8*>(vbp);
        vf[1] = *reinterpret_cast<const bf16x8*>(vbp + 1024);
    };

    // one q-tile x one key-block: QK^T -> exp -> pack -> PV
    auto bodyT = [&](const bf16x8 (&qft)[4], f32x16& ot, float& lA, float& lB,
                     const bf16x8 (&kf)[4], const bf16x8 (&vf)[2]) {
        f32x16 s = {};
        #pragma unroll
        for (int c = 0; c < 4; ++c)
            s = __builtin_amdgcn_mfma_f32_32x32x16_bf16(kf[c], qft[c], s, 0, 0, 0);
        float p[16];
        #pragma unroll
        for (int r = 0; r < 16; ++r) p[r] = __builtin_amdgcn_exp2f(s[r]);
        #pragma unroll
        for (int r = 0; r < 8; ++r) { lA += p[r]; lB += p[r + 8]; }
        union { u32 u[4]; bf16x8 v; } pb0, pb1;
        {
            u32 x0 = cvt_pk_bf16(p[0], p[1]);
            u32 x1 = cvt_pk_bf16(p[2], p[3]);
            u32 y0 = cvt_pk_bf16(p[4], p[5]);
            u32 y1 = cvt_pk_bf16(p[6], p[7]);
            permswap32(x0, y0);
            permswap32(x1, y1);
            pb0.u[0] = x0; pb0.u[1] = x1; pb0.u[2] = y0; pb0.u[3] = y1;
        }
        {
            u32 x0 = cvt_pk_bf16(p[8],  p[9]);
            u32 x1 = cvt_pk_bf16(p[10], p[11]);
            u32 y0 = cvt_pk_bf16(p[12], p[13]);
            u32 y1 = cvt_pk_bf16(p[14], p[15]);
            permswap32(x0, y0);
            permswap32(x1, y1);
            pb1.u[0] = x0; pb1.u[1] = x1; pb1.u[2] = y0; pb1.u[3] = y1;
        }
        ot = __builtin_amdgcn_mfma_f32_32x32x16_bf16(vf[0], pb0.v, ot, 0, 0, 0);
        ot = __builtin_amdgcn_mfma_f32_32x32x16_bf16(vf[1], pb1.v, ot, 0, 0, 0);
    };

    // ---- prologue: pair 0 into buf0; pair 1 into regs ----
    gloadPair(kb_begin);
    swritePair(kv[0]);
    gloadPair(npairs > 1 ? kb_begin + 2 : kb_begin);

    int cur = 0;
    bf16x8 kf[4], vf[2];
    for (int r = 0; r < npairs; ++r) {
        __syncthreads();                       // buf[cur] ready for all
        readsub(kv[cur], 0, kf, vf);
        swritePair(kv[cur ^ 1]);               // pair r+1 -> other buffer
        gloadPair(r + 2 < npairs ? kb_begin + 2 * (r + 2) : kb_begin);
        bodyT(qf1, o1, l1A, l1B, kf, vf);
        bodyT(qf2, o2, l2A, l2B, kf, vf);
        readsub(kv[cur], 1, kf, vf);
        bodyT(qf1, o1, l1A, l1B, kf, vf);
        bodyT(qf2, o2, l2A, l2B, kf, vf);
        cur ^= 1;
    }

    // ---- per-wave partials -> global (both tiles) ----
    float l1 = l1A + l1B, l2 = l2A + l2B;
    l1 += __shfl_xor(l1, 32);
    l2 += __shfl_xor(l2, 32);
    if (hi == 0) {
        lP[(size_t)slice * n_map + tile1 * 32 + ql] = l1;
        lP[(size_t)slice * n_map + tile2 * 32 + ql] = l2;
    }
    __hip_bfloat16* ob1 = oP + ((size_t)slice * (n_map >> 5) + tile1) * 1024;
    __hip_bfloat16* ob2 = oP + ((size_t)slice * (n_map >> 5) + tile2) * 1024;
    #pragma unroll
    for (int r = 0; r < 16; ++r) {
        const int vr = (r & 3) + 8 * (r >> 2) + 4 * hi;
        ob1[vr * 32 + ql] = __float2bfloat16(o1[r]);
        ob2[vr * 32 + ql] = __float2bfloat16(o2[r]);
    }
}

// --------------------------------------------------------- combine_epi ----
// grid = ntiles; 256 thr = 4 waves; sums ks slices, then Wo/residual/LN.
__global__ __launch_bounds__(256) void combine_epi(
    const __hip_bfloat16* __restrict__ oP, const float* __restrict__ lP,
    const float* __restrict__ self_score, const float* __restrict__ gated_map,
    const float* __restrict__ map_code, const float* __restrict__ Wo,
    const float* __restrict__ bo, const float* __restrict__ gamma,
    const float* __restrict__ beta, float* __restrict__ out,
    int n_map, int ks)
{
    const int tid  = threadIdx.x;
    const int w    = tid >> 6;
    const int lane = tid & 63;
    const int T    = blockIdx.x;
    const int q0   = T * 32;
    const int ntiles = n_map >> 5;

    __shared__ float aggT[32][33];
    __shared__ float invS[32];
    __shared__ float psS[32];

    if (tid < 32) {
        const float ps = __builtin_amdgcn_exp2f(self_score[q0 + tid] * IT);
        psS[tid] = ps;
        float l = ps;
        for (int s = 0; s < ks; ++s)
            l += lP[(size_t)s * n_map + q0 + tid];
        invS[tid] = 1.0f / l;
    }
    __syncthreads();

    #pragma unroll
    for (int t = tid; t < 1024; t += 256) {
        const int v  = t >> 5;
        const int qq = t & 31;
        float a = psS[qq] * gated_map[(size_t)(q0 + qq) * 32 + v];
        for (int s = 0; s < ks; ++s)
            a += __bfloat162float(oP[((size_t)s * ntiles + T) * 1024 + t]);
        aggT[v][qq] = a;
    }
    __syncthreads();

    float wo[32];
    #pragma unroll
    for (int vv = 0; vv < 32; ++vv) wo[vv] = Wo[vv * 64 + lane];
    const float bo_e = bo[lane], ga = gamma[lane], be = beta[lane];

    #pragma unroll
    for (int i = 0; i < 8; ++i) {
        const int qq = w * 8 + i;
        float dot = 0.0f;
        #pragma unroll
        for (int vv = 0; vv < 32; ++vv)
            dot = fmaf(aggT[vv][qq], wo[vv], dot); // LDS broadcast reads
        float acc = dot * invS[qq] + bo_e + map_code[(size_t)(q0 + qq) * 64 + lane];
        float mu = acc;
        #pragma unroll
        for (int off = 32; off; off >>= 1) mu += __shfl_xor(mu, off);
        mu *= (1.0f / 64.0f);
        const float dc = acc - mu;
        float var = dc * dc;
        #pragma unroll
        for (int off = 32; off; off >>= 1) var += __shfl_xor(var, off);
        var *= (1.0f / 64.0f);
        out[(size_t)(q0 + qq) * 64 + lane] =
            dc * rsqrtf(var + 1e-6f) * ga + be;
    }
}

// -------------------------------------------------------------- launch ----
extern "C" void kernel_launch(void* const* d_in, const int* in_sizes, int n_in,
                              void* d_out, int out_size, void* d_ws, size_t ws_size,
                              hipStream_t stream) {
    const float* map_code = (const float*)d_in[0];
    const float* obs_code = (const float*)d_in[1];
    const float* Wq  = (const float*)d_in[2];
    const float* Wk  = (const float*)d_in[3];
    const float* Wv  = (const float*)d_in[4];
    const float* Wo  = (const float*)d_in[5];
    const float* bo  = (const float*)d_in[6];
    const float* gam = (const float*)d_in[7];
    const float* bet = (const float*)d_in[8];
    const int n_map = in_sizes[0] / 64;   // 16384
    const int n_obs = in_sizes[1] / 64;   // 8192
    const int ntiles = n_map / 32;        // 512

    char* ws = (char*)d_ws;
    __hip_bfloat16* qbf = (__hip_bfloat16*)ws; ws += (size_t)n_map * 64 * 2;
    __hip_bfloat16* Kp  = (__hip_bfloat16*)ws; ws += (size_t)n_obs * 64 * 2;
    __hip_bfloat16* Vp  = (__hip_bfloat16*)ws; ws += (size_t)n_obs * 32 * 2;
    float* self_score   = (float*)ws;          ws += (size_t)n_map * 4;
    float* gated_map    = (float*)ws;          ws += (size_t)n_map * 32 * 4;
    const size_t base   = (size_t)(ws - (char*)d_ws);
    // per-slice partial cost: oP (n_map*32 bf16) + lP (n_map f32)
    const size_t per_slice = (size_t)n_map * 32 * 2 + (size_t)n_map * 4;
    int kslog = 4;   // ks=16 -> grid 1024 = 4 blocks/CU
    while (kslog > 0 && base + ((size_t)1 << kslog) * per_slice > ws_size)
        --kslog;
    const int ks = 1 << kslog;
    __hip_bfloat16* oP = (__hip_bfloat16*)ws; ws += (size_t)ks * n_map * 32 * 2;
    float* lP = (float*)ws;  // ks * n_map * 4

    const int total = n_map + n_obs;
    prep_kernel<<<(total + 31) / 32, 256, 0, stream>>>(
        map_code, obs_code, Wq, Wk, Wv, qbf, Kp, Vp, self_score, gated_map,
        n_map, n_obs);
    attn_partial<<<(n_map / 256) * ks, 64 * WAVES, 0, stream>>>(
        qbf, Kp, Vp, oP, lP, n_obs, n_map, kslog);
    combine_epi<<<ntiles, 256, 0, stream>>>(
        oP, lP, self_score, gated_map, map_code, Wo, bo, gam, bet,
        (float*)d_out, n_map, ks);
}

// Round 13
// 100.489 us; speedup vs baseline: 1.1697x; 1.1697x over previous
//
#include <hip/hip_runtime.h>
#include <hip/hip_bf16.h>

// Fused map-obs attention (Attention_5815385719367), MI355X/gfx950.
// R13: R12's 2-tile/wave spilled to scratch (FETCH 84MB/WRITE 100MB) ->
// reverted to 1 tile/wave. New structure: ks=32 => slice = 256 keys =
// 48KB packed K/V = fits LDS whole. Stage once (cooperative 48KB copy),
// ONE barrier, then 8 barrier-free bodies per wave from read-only LDS.
// 8-wave blocks (block = 8 q-tiles = 256 rows): grid 64*32 = 2048,
// LDS 48KB -> 3 blocks/CU x 8 waves = 24 waves/CU (75%), staging traffic
// halved. Partial tax (34MB bf16) accepted vs barrier-stall removal.
//
// ws layout (~41 MB; kslog auto-drops if ws_size is short):
//   qbf  [n_map][64] bf16 (pre-scaled by IT)
//   Kp   [n_obs/32][4][64][8] bf16    (packed K fragments, 4KB/kb)
//   Vp   [n_obs/32][2][64][8] bf16    (packed V^T fragments, 2KB/kb)
//   self_score[n_map] f32, gated_map[n_map][32] f32
//   oP [ks][ntiles][32][32] bf16,  lP [ks][n_map] f32

typedef float f32x16 __attribute__((ext_vector_type(16)));
typedef short bf16x8 __attribute__((ext_vector_type(8)));
typedef unsigned int u32;

__device__ __forceinline__ u32 cvt_pk_bf16(float lo, float hi) {
    u32 r;
    asm("v_cvt_pk_bf16_f32 %0, %1, %2" : "=v"(r) : "v"(lo), "v"(hi));
    return r;
}
__device__ __forceinline__ void permswap32(u32& a, u32& b) {
    asm("v_permlane32_swap_b32 %0, %1" : "+v"(a), "+v"(b));
}

#define IT 0.18033688011112042f  // log2(e)/TEMPERATURE, T=8
#define LOG2E 1.44269504089f

// ---------------------------------------------------------------- prep ----
// 256 thr = 4 waves; wave handles 8 rows (32 rows/block), d-loop outer.
__global__ __launch_bounds__(256) void prep_kernel(
    const float* __restrict__ map_code, const float* __restrict__ obs_code,
    const float* __restrict__ Wq, const float* __restrict__ Wk,
    const float* __restrict__ Wv,
    __hip_bfloat16* __restrict__ qbf, __hip_bfloat16* __restrict__ Kp,
    __hip_bfloat16* __restrict__ Vp, float* __restrict__ self_score,
    float* __restrict__ gated_map, int n_map, int n_obs)
{
    __shared__ float xs[32 * 64];
    const int t = threadIdx.x;
    const int w = t >> 6;
    const int e = t & 63;
    const int r0 = blockIdx.x * 32;
    const int total = n_map + n_obs;

    // stage 32 rows of concat(map, obs), coalesced
    #pragma unroll
    for (int i = 0; i < 8; ++i) {
        const int idx = i * 256 + t;
        const int gr = r0 + (idx >> 6);
        const int col = idx & 63;
        float val = 0.0f;
        if (gr < n_map)      val = map_code[(size_t)gr * 64 + col];
        else if (gr < total) val = obs_code[(size_t)(gr - n_map) * 64 + col];
        xs[idx] = val;
    }
    __syncthreads();

    float qa[8] = {}, ka[8] = {}, va[8] = {};
    const float* xw = xs + (w * 8) * 64;
    #pragma unroll 4
    for (int d = 0; d < 64; ++d) {
        const float wq = Wq[d * 64 + e];
        const float wk = Wk[d * 64 + e];
        const float wv = Wv[d * 64 + e];
        #pragma unroll
        for (int i = 0; i < 8; ++i) {
            const float x = xw[i * 64 + d];   // LDS broadcast
            qa[i] = fmaf(x, wq, qa[i]);
            ka[i] = fmaf(x, wk, ka[i]);
            va[i] = fmaf(x, wv, va[i]);
        }
    }

    #pragma unroll
    for (int i = 0; i < 8; ++i) {
        const int r = r0 + w * 8 + i;
        if (r >= total) break;
        const bool is_map = r < n_map;
        // GLU: lanes 0..31 hold a=v[e], need b=v[e+32]
        const float vother = __shfl_xor(va[i], 32);
        const float sig = 1.0f / (1.0f + __builtin_amdgcn_exp2f(-vother * LOG2E));
        const float g = va[i] * sig; // valid for lanes e < 32

        if (is_map) {
            qbf[(size_t)r * 64 + e] = __float2bfloat16(qa[i] * IT);
            float qk = qa[i] * ka[i];
            #pragma unroll
            for (int off = 32; off; off >>= 1) qk += __shfl_xor(qk, off);
            if (e == 0) self_score[r] = qk;
            if (e < 32) gated_map[(size_t)r * 32 + e] = g;
        } else {
            const int j  = r - n_map;          // key index
            const int kb = j >> 5, jq = j & 31;
            {   // Kp: thread e holds K[j][d=e]
                const int c = e >> 4, h2 = (e >> 3) & 1, ii = e & 7;
                Kp[(size_t)kb * 2048 + c * 512 + (h2 * 32 + jq) * 8 + ii] =
                    __float2bfloat16(ka[i]);
            }
            if (e < 32) {  // Vp: thread e holds gated[key=j][vdim=e]
                const int h = jq >> 4, h3 = (jq >> 3) & 1, ii = jq & 7;
                Vp[(size_t)kb * 1024 + h * 512 + (h3 * 32 + e) * 8 + ii] =
                    __float2bfloat16(g);
            }
        }
    }
}

// -------------------------------------------------------------- attn ------
// grid = (n_map/256) * ks. Block: qb = bid>>kslog (8 q-tiles = 256 rows),
// slice = bid & (ks-1); wave w owns q-tile qb*8+w. The slice's packed K/V
// (48KB at ks=32) is staged to LDS with ONE cooperative copy + ONE barrier,
// then each wave runs its 8 bodies barrier-free from read-only LDS.
// (Chunked loop handles nkb>8 if kslog falls back below 5.)
// Swapped QK^T (Q pre-scaled by IT), O^T orientation, no-max softmax.
#define WAVES 8
__global__ __launch_bounds__(64 * WAVES, 4) void attn_partial(
    const __hip_bfloat16* __restrict__ qbf, const __hip_bfloat16* __restrict__ Kp,
    const __hip_bfloat16* __restrict__ Vp,
    __hip_bfloat16* __restrict__ oP, float* __restrict__ lP,
    int n_obs, int n_map, int kslog)
{
    const int tid  = threadIdx.x;
    const int w    = tid >> 6;
    const int lane = tid & 63;
    const int ql   = lane & 31;
    const int hi   = lane >> 5;
    const int ks   = 1 << kslog;
    const int qb   = blockIdx.x >> kslog;
    const int slice= blockIdx.x & (ks - 1);
    const int tileT= qb * WAVES + w;           // global q-tile index
    const int q    = tileT * 32 + ql;

    // whole-slice K/V staging: K 32KB | V 16KB (8 key-blocks)
    __shared__ __align__(16) char kl[32768 + 16384];
    char* vl = kl + 32768;

    // Q fragments: qf[c][j] = (IT*Q)[q][16c + 8hi + j]
    bf16x8 qf[4];
    {
        const __hip_bfloat16* qrow = qbf + (size_t)q * 64 + 8 * hi;
        #pragma unroll
        for (int c = 0; c < 4; ++c)
            qf[c] = *reinterpret_cast<const bf16x8*>(qrow + c * 16);
    }

    float lsumA = 0.0f, lsumB = 0.0f;
    f32x16 o = {};

    const int nkb      = (n_obs >> kslog) >> 5;   // key-blocks per slice
    const int kb_begin = slice * nkb;
    const char* Kb = (const char*)Kp;
    const char* Vb = (const char*)Vp;

    auto body = [&](const bf16x8 (&kf)[4], const bf16x8 (&vf)[2]) {
        // ---- QK^T (swapped): S^T[key][q], pre-scaled by IT ----
        f32x16 s = {};
        #pragma unroll
        for (int c = 0; c < 4; ++c)
            s = __builtin_amdgcn_mfma_f32_32x32x16_bf16(kf[c], qf[c], s, 0, 0, 0);
        // ---- p = 2^s (args bounded; raw HW exp) ----
        float p[16];
        #pragma unroll
        for (int r = 0; r < 16; ++r) p[r] = __builtin_amdgcn_exp2f(s[r]);
        #pragma unroll
        for (int r = 0; r < 8; ++r) { lsumA += p[r]; lsumB += p[r + 8]; }
        // ---- P -> bf16 PV fragments (cvt_pk + permlane32_swap) ----
        union { u32 u[4]; bf16x8 v; } pb0, pb1;
        {
            u32 x0 = cvt_pk_bf16(p[0], p[1]);
            u32 x1 = cvt_pk_bf16(p[2], p[3]);
            u32 y0 = cvt_pk_bf16(p[4], p[5]);
            u32 y1 = cvt_pk_bf16(p[6], p[7]);
            permswap32(x0, y0);
            permswap32(x1, y1);
            pb0.u[0] = x0; pb0.u[1] = x1; pb0.u[2] = y0; pb0.u[3] = y1;
        }
        {
            u32 x0 = cvt_pk_bf16(p[8],  p[9]);
            u32 x1 = cvt_pk_bf16(p[10], p[11]);
            u32 y0 = cvt_pk_bf16(p[12], p[13]);
            u32 y1 = cvt_pk_bf16(p[14], p[15]);
            permswap32(x0, y0);
            permswap32(x1, y1);
            pb1.u[0] = x0; pb1.u[1] = x1; pb1.u[2] = y0; pb1.u[3] = y1;
        }
        // ---- PV: O^T += V^T x P^T ----
        o = __builtin_amdgcn_mfma_f32_32x32x16_bf16(vf[0], pb0.v, o, 0, 0, 0);
        o = __builtin_amdgcn_mfma_f32_32x32x16_bf16(vf[1], pb1.v, o, 0, 0, 0);
    };

    // ---- chunks of 8 key-blocks: stage 48KB, 1 barrier, 8 bodies/wave ----
    for (int c0 = 0; c0 < nkb; c0 += 8) {
        if (c0) __syncthreads();               // prior chunk's reads done
        const char* Ks = Kb + (size_t)(kb_begin + c0) * 4096;
        const char* Vs = Vb + (size_t)(kb_begin + c0) * 2048;
        #pragma unroll
        for (int i = 0; i < 4; ++i) {          // K: 2048 x 16B
            const int idx = i * 512 + tid;
            *reinterpret_cast<uint4*>(kl + idx * 16) =
                *reinterpret_cast<const uint4*>(Ks + idx * 16);
        }
        #pragma unroll
        for (int i = 0; i < 2; ++i) {          // V: 1024 x 16B
            const int idx = i * 512 + tid;
            *reinterpret_cast<uint4*>(vl + idx * 16) =
                *reinterpret_cast<const uint4*>(Vs + idx * 16);
        }
        __syncthreads();

        #pragma unroll 2
        for (int kb = 0; kb < 8; ++kb) {
            bf16x8 kf[4], vf[2];
            const char* kbp = kl + kb * 4096 + lane * 16;
            #pragma unroll
            for (int c = 0; c < 4; ++c)
                kf[c] = *reinterpret_cast<const bf16x8*>(kbp + c * 1024);
            const char* vbp = vl + kb * 2048 + lane * 16;
            vf[0] = *reinterpret_cast<const bf16x8*>(vbp);
            vf[1] = *reinterpret_cast<const bf16x8*>(vbp + 1024);
            body(kf, vf);
        }
    }

    // ---- per-wave partials -> global ----
    float lsum = lsumA + lsumB;
    lsum += __shfl_xor(lsum, 32);   // combine key-halves
    if (hi == 0) lP[(size_t)slice * n_map + tileT * 32 + ql] = lsum;
    __hip_bfloat16* ob = oP + ((size_t)slice * (n_map >> 5) + tileT) * 1024;
    #pragma unroll
    for (int r = 0; r < 16; ++r) {
        const int vr = (r & 3) + 8 * (r >> 2) + 4 * hi;
        ob[vr * 32 + ql] = __float2bfloat16(o[r]);
    }
}

// --------------------------------------------------------- combine_epi ----
// grid = ntiles; 256 thr = 4 waves; sums ks slices, then Wo/residual/LN.
__global__ __launch_bounds__(256) void combine_epi(
    const __hip_bfloat16* __restrict__ oP, const float* __restrict__ lP,
    const float* __restrict__ self_score, const float* __restrict__ gated_map,
    const float* __restrict__ map_code, const float* __restrict__ Wo,
    const float* __restrict__ bo, const float* __restrict__ gamma,
    const float* __restrict__ beta, float* __restrict__ out,
    int n_map, int ks)
{
    const int tid  = threadIdx.x;
    const int w    = tid >> 6;
    const int lane = tid & 63;
    const int T    = blockIdx.x;
    const int q0   = T * 32;
    const int ntiles = n_map >> 5;

    __shared__ float aggT[32][33];
    __shared__ float invS[32];
    __shared__ float psS[32];

    if (tid < 32) {
        const float ps = __builtin_amdgcn_exp2f(self_score[q0 + tid] * IT);
        psS[tid] = ps;
        float l = ps;
        for (int s = 0; s < ks; ++s)
            l += lP[(size_t)s * n_map + q0 + tid];
        invS[tid] = 1.0f / l;
    }
    __syncthreads();

    #pragma unroll
    for (int t = tid; t < 1024; t += 256) {
        const int v  = t >> 5;
        const int qq = t & 31;
        float a = psS[qq] * gated_map[(size_t)(q0 + qq) * 32 + v];
        for (int s = 0; s < ks; ++s)
            a += __bfloat162float(oP[((size_t)s * ntiles + T) * 1024 + t]);
        aggT[v][qq] = a;
    }
    __syncthreads();

    float wo[32];
    #pragma unroll
    for (int vv = 0; vv < 32; ++vv) wo[vv] = Wo[vv * 64 + lane];
    const float bo_e = bo[lane], ga = gamma[lane], be = beta[lane];

    #pragma unroll
    for (int i = 0; i < 8; ++i) {
        const int qq = w * 8 + i;
        float dot = 0.0f;
        #pragma unroll
        for (int vv = 0; vv < 32; ++vv)
            dot = fmaf(aggT[vv][qq], wo[vv], dot); // LDS broadcast reads
        float acc = dot * invS[qq] + bo_e + map_code[(size_t)(q0 + qq) * 64 + lane];
        float mu = acc;
        #pragma unroll
        for (int off = 32; off; off >>= 1) mu += __shfl_xor(mu, off);
        mu *= (1.0f / 64.0f);
        const float dc = acc - mu;
        float var = dc * dc;
        #pragma unroll
        for (int off = 32; off; off >>= 1) var += __shfl_xor(var, off);
        var *= (1.0f / 64.0f);
        out[(size_t)(q0 + qq) * 64 + lane] =
            dc * rsqrtf(var + 1e-6f) * ga + be;
    }
}

// -------------------------------------------------------------- launch ----
extern "C" void kernel_launch(void* const* d_in, const int* in_sizes, int n_in,
                              void* d_out, int out_size, void* d_ws, size_t ws_size,
                              hipStream_t stream) {
    const float* map_code = (const float*)d_in[0];
    const float* obs_code = (const float*)d_in[1];
    const float* Wq  = (const float*)d_in[2];
    const float* Wk  = (const float*)d_in[3];
    const float* Wv  = (const float*)d_in[4];
    const float* Wo  = (const float*)d_in[5];
    const float* bo  = (const float*)d_in[6];
    const float* gam = (const float*)d_in[7];
    const float* bet = (const float*)d_in[8];
    const int n_map = in_sizes[0] / 64;   // 16384
    const int n_obs = in_sizes[1] / 64;   // 8192
    const int ntiles = n_map / 32;        // 512

    char* ws = (char*)d_ws;
    __hip_bfloat16* qbf = (__hip_bfloat16*)ws; ws += (size_t)n_map * 64 * 2;
    __hip_bfloat16* Kp  = (__hip_bfloat16*)ws; ws += (size_t)n_obs * 64 * 2;
    __hip_bfloat16* Vp  = (__hip_bfloat16*)ws; ws += (size_t)n_obs * 32 * 2;
    float* self_score   = (float*)ws;          ws += (size_t)n_map * 4;
    float* gated_map    = (float*)ws;          ws += (size_t)n_map * 32 * 4;
    const size_t base   = (size_t)(ws - (char*)d_ws);
    // per-slice partial cost: oP (n_map*32 bf16) + lP (n_map f32)
    const size_t per_slice = (size_t)n_map * 32 * 2 + (size_t)n_map * 4;
    int kslog = 5;   // ks=32 -> slice = 256 keys = 48KB (whole-slice LDS)
    while (kslog > 0 && base + ((size_t)1 << kslog) * per_slice > ws_size)
        --kslog;
    const int ks = 1 << kslog;
    __hip_bfloat16* oP = (__hip_bfloat16*)ws; ws += (size_t)ks * n_map * 32 * 2;
    float* lP = (float*)ws;  // ks * n_map * 4

    const int total = n_map + n_obs;
    prep_kernel<<<(total + 31) / 32, 256, 0, stream>>>(
        map_code, obs_code, Wq, Wk, Wv, qbf, Kp, Vp, self_score, gated_map,
        n_map, n_obs);
    attn_partial<<<(n_map / 256) * ks, 64 * WAVES, 0, stream>>>(
        qbf, Kp, Vp, oP, lP, n_obs, n_map, kslog);
    combine_epi<<<ntiles, 256, 0, stream>>>(
        oP, lP, self_score, gated_map, map_code, Wo, bo, gam, bet,
        (float*)d_out, n_map, ks);
}

// Round 14
// 67.350 us; speedup vs baseline: 1.7452x; 1.4920x over previous
//
#include <hip/hip_runtime.h>
#include <hip/hip_bf16.h>

// Fused map-obs attention (Attention_5815385719367), MI355X/gfx950.
// R14: R13's combine_epi was the regression (50.5us: 19% occ, scalar bf16
// loads, 32-deep serial slice loop, 128B-strided gated_map). Split into:
//  (1) reduce_oP: streaming slice-reduction, 8 elems/thread via uint4
//      (8xbf16) loads, unroll-4 for MLP, self-term folded in (coalesced via
//      pself[] and TRANSPOSED gmT[32][n_map]); writes f32 agg (2MB).
//  (2) epilogue: parallel lP reduce + LDS-staged agg + Wo/residual/LN.
// attn_partial kept from R13 (whole-slice 48KB LDS, 1 barrier / 8 bodies).
//
// ws layout (~42 MB; kslog auto-drops if ws_size is short):
//   qbf  [n_map][64] bf16 (pre-scaled by IT)
//   Kp   [n_obs/32][4][64][8] bf16, Vp [n_obs/32][2][64][8] bf16
//   pself[n_map] f32, gmT[32][n_map] f32, agg[ntiles*1024] f32
//   oP [ks][ntiles][32][32] bf16,  lP [ks][n_map] f32

typedef float f32x16 __attribute__((ext_vector_type(16)));
typedef short bf16x8 __attribute__((ext_vector_type(8)));
typedef unsigned int u32;

__device__ __forceinline__ u32 cvt_pk_bf16(float lo, float hi) {
    u32 r;
    asm("v_cvt_pk_bf16_f32 %0, %1, %2" : "=v"(r) : "v"(lo), "v"(hi));
    return r;
}
__device__ __forceinline__ void permswap32(u32& a, u32& b) {
    asm("v_permlane32_swap_b32 %0, %1" : "+v"(a), "+v"(b));
}

#define IT 0.18033688011112042f  // log2(e)/TEMPERATURE, T=8
#define LOG2E 1.44269504089f

// ---------------------------------------------------------------- prep ----
// 256 thr = 4 waves; wave handles 8 rows (32 rows/block), d-loop outer.
__global__ __launch_bounds__(256) void prep_kernel(
    const float* __restrict__ map_code, const float* __restrict__ obs_code,
    const float* __restrict__ Wq, const float* __restrict__ Wk,
    const float* __restrict__ Wv,
    __hip_bfloat16* __restrict__ qbf, __hip_bfloat16* __restrict__ Kp,
    __hip_bfloat16* __restrict__ Vp, float* __restrict__ pself,
    float* __restrict__ gmT, int n_map, int n_obs)
{
    __shared__ float xs[32 * 64];
    const int t = threadIdx.x;
    const int w = t >> 6;
    const int e = t & 63;
    const int r0 = blockIdx.x * 32;
    const int total = n_map + n_obs;

    // stage 32 rows of concat(map, obs), coalesced
    #pragma unroll
    for (int i = 0; i < 8; ++i) {
        const int idx = i * 256 + t;
        const int gr = r0 + (idx >> 6);
        const int col = idx & 63;
        float val = 0.0f;
        if (gr < n_map)      val = map_code[(size_t)gr * 64 + col];
        else if (gr < total) val = obs_code[(size_t)(gr - n_map) * 64 + col];
        xs[idx] = val;
    }
    __syncthreads();

    float qa[8] = {}, ka[8] = {}, va[8] = {};
    const float* xw = xs + (w * 8) * 64;
    #pragma unroll 4
    for (int d = 0; d < 64; ++d) {
        const float wq = Wq[d * 64 + e];
        const float wk = Wk[d * 64 + e];
        const float wv = Wv[d * 64 + e];
        #pragma unroll
        for (int i = 0; i < 8; ++i) {
            const float x = xw[i * 64 + d];   // LDS broadcast
            qa[i] = fmaf(x, wq, qa[i]);
            ka[i] = fmaf(x, wk, ka[i]);
            va[i] = fmaf(x, wv, va[i]);
        }
    }

    #pragma unroll
    for (int i = 0; i < 8; ++i) {
        const int r = r0 + w * 8 + i;
        if (r >= total) break;
        const bool is_map = r < n_map;
        // GLU: lanes 0..31 hold a=v[e], need b=v[e+32]
        const float vother = __shfl_xor(va[i], 32);
        const float sig = 1.0f / (1.0f + __builtin_amdgcn_exp2f(-vother * LOG2E));
        const float g = va[i] * sig; // valid for lanes e < 32

        if (is_map) {
            qbf[(size_t)r * 64 + e] = __float2bfloat16(qa[i] * IT);
            float qk = qa[i] * ka[i];
            #pragma unroll
            for (int off = 32; off; off >>= 1) qk += __shfl_xor(qk, off);
            if (e == 0) pself[r] = __builtin_amdgcn_exp2f(qk * IT);
            if (e < 32) gmT[(size_t)e * n_map + r] = g;   // transposed
        } else {
            const int j  = r - n_map;          // key index
            const int kb = j >> 5, jq = j & 31;
            {   // Kp: thread e holds K[j][d=e]
                const int c = e >> 4, h2 = (e >> 3) & 1, ii = e & 7;
                Kp[(size_t)kb * 2048 + c * 512 + (h2 * 32 + jq) * 8 + ii] =
                    __float2bfloat16(ka[i]);
            }
            if (e < 32) {  // Vp: thread e holds gated[key=j][vdim=e]
                const int h = jq >> 4, h3 = (jq >> 3) & 1, ii = jq & 7;
                Vp[(size_t)kb * 1024 + h * 512 + (h3 * 32 + e) * 8 + ii] =
                    __float2bfloat16(g);
            }
        }
    }
}

// -------------------------------------------------------------- attn ------
// (unchanged from R13) grid = (n_map/256) * ks; 8 waves; whole-slice 48KB
// LDS staging, 1 barrier per 8-kb chunk, barrier-free bodies.
#define WAVES 8
__global__ __launch_bounds__(64 * WAVES, 4) void attn_partial(
    const __hip_bfloat16* __restrict__ qbf, const __hip_bfloat16* __restrict__ Kp,
    const __hip_bfloat16* __restrict__ Vp,
    __hip_bfloat16* __restrict__ oP, float* __restrict__ lP,
    int n_obs, int n_map, int kslog)
{
    const int tid  = threadIdx.x;
    const int w    = tid >> 6;
    const int lane = tid & 63;
    const int ql   = lane & 31;
    const int hi   = lane >> 5;
    const int qb   = blockIdx.x >> kslog;
    const int slice= blockIdx.x & ((1 << kslog) - 1);
    const int tileT= qb * WAVES + w;           // global q-tile index
    const int q    = tileT * 32 + ql;

    __shared__ __align__(16) char kl[32768 + 16384];
    char* vl = kl + 32768;

    bf16x8 qf[4];
    {
        const __hip_bfloat16* qrow = qbf + (size_t)q * 64 + 8 * hi;
        #pragma unroll
        for (int c = 0; c < 4; ++c)
            qf[c] = *reinterpret_cast<const bf16x8*>(qrow + c * 16);
    }

    float lsumA = 0.0f, lsumB = 0.0f;
    f32x16 o = {};

    const int nkb      = (n_obs >> kslog) >> 5;   // key-blocks per slice
    const int kb_begin = slice * nkb;
    const char* Kb = (const char*)Kp;
    const char* Vb = (const char*)Vp;

    auto body = [&](const bf16x8 (&kf)[4], const bf16x8 (&vf)[2]) {
        f32x16 s = {};
        #pragma unroll
        for (int c = 0; c < 4; ++c)
            s = __builtin_amdgcn_mfma_f32_32x32x16_bf16(kf[c], qf[c], s, 0, 0, 0);
        float p[16];
        #pragma unroll
        for (int r = 0; r < 16; ++r) p[r] = __builtin_amdgcn_exp2f(s[r]);
        #pragma unroll
        for (int r = 0; r < 8; ++r) { lsumA += p[r]; lsumB += p[r + 8]; }
        union { u32 u[4]; bf16x8 v; } pb0, pb1;
        {
            u32 x0 = cvt_pk_bf16(p[0], p[1]);
            u32 x1 = cvt_pk_bf16(p[2], p[3]);
            u32 y0 = cvt_pk_bf16(p[4], p[5]);
            u32 y1 = cvt_pk_bf16(p[6], p[7]);
            permswap32(x0, y0);
            permswap32(x1, y1);
            pb0.u[0] = x0; pb0.u[1] = x1; pb0.u[2] = y0; pb0.u[3] = y1;
        }
        {
            u32 x0 = cvt_pk_bf16(p[8],  p[9]);
            u32 x1 = cvt_pk_bf16(p[10], p[11]);
            u32 y0 = cvt_pk_bf16(p[12], p[13]);
            u32 y1 = cvt_pk_bf16(p[14], p[15]);
            permswap32(x0, y0);
            permswap32(x1, y1);
            pb1.u[0] = x0; pb1.u[1] = x1; pb1.u[2] = y0; pb1.u[3] = y1;
        }
        o = __builtin_amdgcn_mfma_f32_32x32x16_bf16(vf[0], pb0.v, o, 0, 0, 0);
        o = __builtin_amdgcn_mfma_f32_32x32x16_bf16(vf[1], pb1.v, o, 0, 0, 0);
    };

    for (int c0 = 0; c0 < nkb; c0 += 8) {
        if (c0) __syncthreads();
        const char* Ks = Kb + (size_t)(kb_begin + c0) * 4096;
        const char* Vs = Vb + (size_t)(kb_begin + c0) * 2048;
        #pragma unroll
        for (int i = 0; i < 4; ++i) {
            const int idx = i * 512 + tid;
            *reinterpret_cast<uint4*>(kl + idx * 16) =
                *reinterpret_cast<const uint4*>(Ks + idx * 16);
        }
        #pragma unroll
        for (int i = 0; i < 2; ++i) {
            const int idx = i * 512 + tid;
            *reinterpret_cast<uint4*>(vl + idx * 16) =
                *reinterpret_cast<const uint4*>(Vs + idx * 16);
        }
        __syncthreads();

        #pragma unroll 2
        for (int kb = 0; kb < 8; ++kb) {
            bf16x8 kf[4], vf[2];
            const char* kbp = kl + kb * 4096 + lane * 16;
            #pragma unroll
            for (int c = 0; c < 4; ++c)
                kf[c] = *reinterpret_cast<const bf16x8*>(kbp + c * 1024);
            const char* vbp = vl + kb * 2048 + lane * 16;
            vf[0] = *reinterpret_cast<const bf16x8*>(vbp);
            vf[1] = *reinterpret_cast<const bf16x8*>(vbp + 1024);
            body(kf, vf);
        }
    }

    float lsum = lsumA + lsumB;
    lsum += __shfl_xor(lsum, 32);
    if (hi == 0) lP[(size_t)slice * n_map + tileT * 32 + ql] = lsum;
    __hip_bfloat16* ob = oP + ((size_t)slice * (n_map >> 5) + tileT) * 1024;
    #pragma unroll
    for (int r = 0; r < 16; ++r) {
        const int vr = (r & 3) + 8 * (r >> 2) + 4 * hi;
        ob[vr * 32 + ql] = __float2bfloat16(o[r]);
    }
}

// ----------------------------------------------------------- reduce_oP ----
// grid = ntiles*1024/(256*8); thread owns 8 consecutive agg elements.
// agg[T*1024 + t] = pself*gmT + sum_s oP[s][T][t]; uint4 loads, unroll 4.
__global__ __launch_bounds__(256) void reduce_oP(
    const __hip_bfloat16* __restrict__ oP, const float* __restrict__ pself,
    const float* __restrict__ gmT, float* __restrict__ agg,
    int n_map, int ks)
{
    const int gid = blockIdx.x * 256 + threadIdx.x;
    const int e0  = gid * 8;
    const int T   = e0 >> 10;
    const int t0  = e0 & 1023;
    const int v   = t0 >> 5;          // 8 elems stay within one v (8|t0)
    const int qq0 = t0 & 31;
    const int q0  = T * 32 + qq0;
    const int ntiles = n_map >> 5;

    float a[8];
    {
        const float4 ps0 = *reinterpret_cast<const float4*>(pself + q0);
        const float4 ps1 = *reinterpret_cast<const float4*>(pself + q0 + 4);
        const float4 g0  = *reinterpret_cast<const float4*>(gmT + (size_t)v * n_map + q0);
        const float4 g1  = *reinterpret_cast<const float4*>(gmT + (size_t)v * n_map + q0 + 4);
        a[0] = ps0.x * g0.x; a[1] = ps0.y * g0.y;
        a[2] = ps0.z * g0.z; a[3] = ps0.w * g0.w;
        a[4] = ps1.x * g1.x; a[5] = ps1.y * g1.y;
        a[6] = ps1.z * g1.z; a[7] = ps1.w * g1.w;
    }
    const __hip_bfloat16* ob = oP + (size_t)T * 1024 + t0;
    const size_t sstride = (size_t)ntiles * 1024;
    #pragma unroll 4
    for (int s = 0; s < ks; ++s) {
        const uint4 u = *reinterpret_cast<const uint4*>(ob + s * sstride);
        a[0] += __uint_as_float(u.x << 16);
        a[1] += __uint_as_float(u.x & 0xffff0000u);
        a[2] += __uint_as_float(u.y << 16);
        a[3] += __uint_as_float(u.y & 0xffff0000u);
        a[4] += __uint_as_float(u.z << 16);
        a[5] += __uint_as_float(u.z & 0xffff0000u);
        a[6] += __uint_as_float(u.w << 16);
        a[7] += __uint_as_float(u.w & 0xffff0000u);
    }
    float4* dst = reinterpret_cast<float4*>(agg + e0);
    dst[0] = make_float4(a[0], a[1], a[2], a[3]);
    dst[1] = make_float4(a[4], a[5], a[6], a[7]);
}

// ------------------------------------------------------------- epilogue ---
// grid = ntiles; 256 thr = 4 waves. Parallel lP reduce, LDS-staged agg,
// Wo matmul + residual + LayerNorm.
__global__ __launch_bounds__(256) void epilogue(
    const float* __restrict__ agg, const float* __restrict__ lP,
    const float* __restrict__ pself, const float* __restrict__ map_code,
    const float* __restrict__ Wo, const float* __restrict__ bo,
    const float* __restrict__ gamma, const float* __restrict__ beta,
    float* __restrict__ out, int n_map, int ks)
{
    const int tid  = threadIdx.x;
    const int w    = tid >> 6;
    const int lane = tid & 63;
    const int T    = blockIdx.x;
    const int q0   = T * 32;

    __shared__ float aggT[32][33];
    __shared__ float lsumL[8][32];
    __shared__ float invS[32];

    // parallel lP reduction: group g = tid>>5 handles slices g, g+8, ...
    {
        const int g  = tid >> 5;
        const int qq = tid & 31;
        float part = 0.0f;
        for (int s = g; s < ks; s += 8)
            part += lP[(size_t)s * n_map + q0 + qq];
        lsumL[g][qq] = part;
    }
    // stage agg into LDS (coalesced float4)
    {
        const float4 f4 = reinterpret_cast<const float4*>(agg + (size_t)T * 1024)[tid];
        const int v  = tid >> 3;
        const int qq = (tid & 7) * 4;
        aggT[v][qq + 0] = f4.x; aggT[v][qq + 1] = f4.y;
        aggT[v][qq + 2] = f4.z; aggT[v][qq + 3] = f4.w;
    }
    __syncthreads();
    if (tid < 32) {
        float l = pself[q0 + tid];
        #pragma unroll
        for (int g = 0; g < 8; ++g) l += lsumL[g][tid];
        invS[tid] = 1.0f / l;
    }
    __syncthreads();

    float wo[32];
    #pragma unroll
    for (int vv = 0; vv < 32; ++vv) wo[vv] = Wo[vv * 64 + lane];
    const float bo_e = bo[lane], ga = gamma[lane], be = beta[lane];

    #pragma unroll
    for (int i = 0; i < 8; ++i) {
        const int qq = w * 8 + i;
        float dot = 0.0f;
        #pragma unroll
        for (int vv = 0; vv < 32; ++vv)
            dot = fmaf(aggT[vv][qq], wo[vv], dot); // LDS broadcast reads
        float acc = dot * invS[qq] + bo_e + map_code[(size_t)(q0 + qq) * 64 + lane];
        float mu = acc;
        #pragma unroll
        for (int off = 32; off; off >>= 1) mu += __shfl_xor(mu, off);
        mu *= (1.0f / 64.0f);
        const float dc = acc - mu;
        float var = dc * dc;
        #pragma unroll
        for (int off = 32; off; off >>= 1) var += __shfl_xor(var, off);
        var *= (1.0f / 64.0f);
        out[(size_t)(q0 + qq) * 64 + lane] =
            dc * rsqrtf(var + 1e-6f) * ga + be;
    }
}

// -------------------------------------------------------------- launch ----
extern "C" void kernel_launch(void* const* d_in, const int* in_sizes, int n_in,
                              void* d_out, int out_size, void* d_ws, size_t ws_size,
                              hipStream_t stream) {
    const float* map_code = (const float*)d_in[0];
    const float* obs_code = (const float*)d_in[1];
    const float* Wq  = (const float*)d_in[2];
    const float* Wk  = (const float*)d_in[3];
    const float* Wv  = (const float*)d_in[4];
    const float* Wo  = (const float*)d_in[5];
    const float* bo  = (const float*)d_in[6];
    const float* gam = (const float*)d_in[7];
    const float* bet = (const float*)d_in[8];
    const int n_map = in_sizes[0] / 64;   // 16384
    const int n_obs = in_sizes[1] / 64;   // 8192
    const int ntiles = n_map / 32;        // 512

    char* ws = (char*)d_ws;
    __hip_bfloat16* qbf = (__hip_bfloat16*)ws; ws += (size_t)n_map * 64 * 2;
    __hip_bfloat16* Kp  = (__hip_bfloat16*)ws; ws += (size_t)n_obs * 64 * 2;
    __hip_bfloat16* Vp  = (__hip_bfloat16*)ws; ws += (size_t)n_obs * 32 * 2;
    float* pself        = (float*)ws;          ws += (size_t)n_map * 4;
    float* gmT          = (float*)ws;          ws += (size_t)n_map * 32 * 4;
    float* agg          = (float*)ws;          ws += (size_t)ntiles * 1024 * 4;
    const size_t base   = (size_t)(ws - (char*)d_ws);
    // per-slice partial cost: oP (n_map*32 bf16) + lP (n_map f32)
    const size_t per_slice = (size_t)n_map * 32 * 2 + (size_t)n_map * 4;
    int kslog = 5;   // ks=32 -> slice = 256 keys = 48KB (whole-slice LDS)
    while (kslog > 0 && base + ((size_t)1 << kslog) * per_slice > ws_size)
        --kslog;
    const int ks = 1 << kslog;
    __hip_bfloat16* oP = (__hip_bfloat16*)ws; ws += (size_t)ks * n_map * 32 * 2;
    float* lP = (float*)ws;  // ks * n_map * 4

    const int total = n_map + n_obs;
    prep_kernel<<<(total + 31) / 32, 256, 0, stream>>>(
        map_code, obs_code, Wq, Wk, Wv, qbf, Kp, Vp, pself, gmT,
        n_map, n_obs);
    attn_partial<<<(n_map / 256) * ks, 64 * WAVES, 0, stream>>>(
        qbf, Kp, Vp, oP, lP, n_obs, n_map, kslog);
    reduce_oP<<<(ntiles * 1024) / (256 * 8), 256, 0, stream>>>(
        oP, pself, gmT, agg, n_map, ks);
    epilogue<<<ntiles, 256, 0, stream>>>(
        agg, lP, pself, map_code, Wo, bo, gam, bet,
        (float*)d_out, n_map, ks);
}

// Round 15
// 67.052 us; speedup vs baseline: 1.7529x; 1.0044x over previous
//
#include <hip/hip_runtime.h>
#include <hip/hip_bf16.h>

// Fused map-obs attention (Attention_5815385719367), MI355X/gfx950.
// R14: R13's combine_epi was the regression (50.5us: 19% occ, scalar bf16
// loads, 32-deep serial slice loop, 128B-strided gated_map). Split into:
//  (1) reduce_oP: streaming slice-reduction, 8 elems/thread via uint4
//      (8xbf16) loads, unroll-4 for MLP, self-term folded in (coalesced via
//      pself[] and TRANSPOSED gmT[32][n_map]); writes f32 agg (2MB).
//  (2) epilogue: parallel lP reduce + LDS-staged agg + Wo/residual/LN.
// attn_partial kept from R13 (whole-slice 48KB LDS, 1 barrier / 8 bodies).
//
// ws layout (~42 MB; kslog auto-drops if ws_size is short):
//   qbf  [n_map][64] bf16 (pre-scaled by IT)
//   Kp   [n_obs/32][4][64][8] bf16, Vp [n_obs/32][2][64][8] bf16
//   pself[n_map] f32, gmT[32][n_map] f32, agg[ntiles*1024] f32
//   oP [ks][ntiles][32][32] bf16,  lP [ks][n_map] f32

typedef float f32x16 __attribute__((ext_vector_type(16)));
typedef short bf16x8 __attribute__((ext_vector_type(8)));
typedef unsigned int u32;

__device__ __forceinline__ u32 cvt_pk_bf16(float lo, float hi) {
    u32 r;
    asm("v_cvt_pk_bf16_f32 %0, %1, %2" : "=v"(r) : "v"(lo), "v"(hi));
    return r;
}
__device__ __forceinline__ void permswap32(u32& a, u32& b) {
    asm("v_permlane32_swap_b32 %0, %1" : "+v"(a), "+v"(b));
}

#define IT 0.18033688011112042f  // log2(e)/TEMPERATURE, T=8
#define LOG2E 1.44269504089f

// ---------------------------------------------------------------- prep ----
// 256 thr = 4 waves; wave handles 8 rows (32 rows/block), d-loop outer.
__global__ __launch_bounds__(256) void prep_kernel(
    const float* __restrict__ map_code, const float* __restrict__ obs_code,
    const float* __restrict__ Wq, const float* __restrict__ Wk,
    const float* __restrict__ Wv,
    __hip_bfloat16* __restrict__ qbf, __hip_bfloat16* __restrict__ Kp,
    __hip_bfloat16* __restrict__ Vp, float* __restrict__ pself,
    float* __restrict__ gmT, int n_map, int n_obs)
{
    __shared__ float xs[32 * 64];
    const int t = threadIdx.x;
    const int w = t >> 6;
    const int e = t & 63;
    const int r0 = blockIdx.x * 32;
    const int total = n_map + n_obs;

    // stage 32 rows of concat(map, obs), coalesced
    #pragma unroll
    for (int i = 0; i < 8; ++i) {
        const int idx = i * 256 + t;
        const int gr = r0 + (idx >> 6);
        const int col = idx & 63;
        float val = 0.0f;
        if (gr < n_map)      val = map_code[(size_t)gr * 64 + col];
        else if (gr < total) val = obs_code[(size_t)(gr - n_map) * 64 + col];
        xs[idx] = val;
    }
    __syncthreads();

    float qa[8] = {}, ka[8] = {}, va[8] = {};
    const float* xw = xs + (w * 8) * 64;
    #pragma unroll 4
    for (int d = 0; d < 64; ++d) {
        const float wq = Wq[d * 64 + e];
        const float wk = Wk[d * 64 + e];
        const float wv = Wv[d * 64 + e];
        #pragma unroll
        for (int i = 0; i < 8; ++i) {
            const float x = xw[i * 64 + d];   // LDS broadcast
            qa[i] = fmaf(x, wq, qa[i]);
            ka[i] = fmaf(x, wk, ka[i]);
            va[i] = fmaf(x, wv, va[i]);
        }
    }

    #pragma unroll
    for (int i = 0; i < 8; ++i) {
        const int r = r0 + w * 8 + i;
        if (r >= total) break;
        const bool is_map = r < n_map;
        // GLU: lanes 0..31 hold a=v[e], need b=v[e+32]
        const float vother = __shfl_xor(va[i], 32);
        const float sig = 1.0f / (1.0f + __builtin_amdgcn_exp2f(-vother * LOG2E));
        const float g = va[i] * sig; // valid for lanes e < 32

        if (is_map) {
            qbf[(size_t)r * 64 + e] = __float2bfloat16(qa[i] * IT);
            float qk = qa[i] * ka[i];
            #pragma unroll
            for (int off = 32; off; off >>= 1) qk += __shfl_xor(qk, off);
            if (e == 0) pself[r] = __builtin_amdgcn_exp2f(qk * IT);
            if (e < 32) gmT[(size_t)e * n_map + r] = g;   // transposed
        } else {
            const int j  = r - n_map;          // key index
            const int kb = j >> 5, jq = j & 31;
            {   // Kp: thread e holds K[j][d=e]
                const int c = e >> 4, h2 = (e >> 3) & 1, ii = e & 7;
                Kp[(size_t)kb * 2048 + c * 512 + (h2 * 32 + jq) * 8 + ii] =
                    __float2bfloat16(ka[i]);
            }
            if (e < 32) {  // Vp: thread e holds gated[key=j][vdim=e]
                const int h = jq >> 4, h3 = (jq >> 3) & 1, ii = jq & 7;
                Vp[(size_t)kb * 1024 + h * 512 + (h3 * 32 + e) * 8 + ii] =
                    __float2bfloat16(g);
            }
        }
    }
}

// -------------------------------------------------------------- attn ------
// (unchanged from R13) grid = (n_map/256) * ks; 8 waves; whole-slice 48KB
// LDS staging, 1 barrier per 8-kb chunk, barrier-free bodies.
#define WAVES 8
__global__ __launch_bounds__(64 * WAVES, 4) void attn_partial(
    const __hip_bfloat16* __restrict__ qbf, const __hip_bfloat16* __restrict__ Kp,
    const __hip_bfloat16* __restrict__ Vp,
    __hip_bfloat16* __restrict__ oP, float* __restrict__ lP,
    int n_obs, int n_map, int kslog)
{
    const int tid  = threadIdx.x;
    const int w    = tid >> 6;
    const int lane = tid & 63;
    const int ql   = lane & 31;
    const int hi   = lane >> 5;
    const int qb   = blockIdx.x >> kslog;
    const int slice= blockIdx.x & ((1 << kslog) - 1);
    const int tileT= qb * WAVES + w;           // global q-tile index
    const int q    = tileT * 32 + ql;

    __shared__ __align__(16) char kl[32768 + 16384];
    char* vl = kl + 32768;

    bf16x8 qf[4];
    {
        const __hip_bfloat16* qrow = qbf + (size_t)q * 64 + 8 * hi;
        #pragma unroll
        for (int c = 0; c < 4; ++c)
            qf[c] = *reinterpret_cast<const bf16x8*>(qrow + c * 16);
    }

    float lsumA = 0.0f, lsumB = 0.0f;
    f32x16 o = {};

    const int nkb      = (n_obs >> kslog) >> 5;   // key-blocks per slice
    const int kb_begin = slice * nkb;
    const char* Kb = (const char*)Kp;
    const char* Vb = (const char*)Vp;

    auto body = [&](const bf16x8 (&kf)[4], const bf16x8 (&vf)[2]) {
        f32x16 s = {};
        #pragma unroll
        for (int c = 0; c < 4; ++c)
            s = __builtin_amdgcn_mfma_f32_32x32x16_bf16(kf[c], qf[c], s, 0, 0, 0);
        float p[16];
        #pragma unroll
        for (int r = 0; r < 16; ++r) p[r] = __builtin_amdgcn_exp2f(s[r]);
        #pragma unroll
        for (int r = 0; r < 8; ++r) { lsumA += p[r]; lsumB += p[r + 8]; }
        union { u32 u[4]; bf16x8 v; } pb0, pb1;
        {
            u32 x0 = cvt_pk_bf16(p[0], p[1]);
            u32 x1 = cvt_pk_bf16(p[2], p[3]);
            u32 y0 = cvt_pk_bf16(p[4], p[5]);
            u32 y1 = cvt_pk_bf16(p[6], p[7]);
            permswap32(x0, y0);
            permswap32(x1, y1);
            pb0.u[0] = x0; pb0.u[1] = x1; pb0.u[2] = y0; pb0.u[3] = y1;
        }
        {
            u32 x0 = cvt_pk_bf16(p[8],  p[9]);
            u32 x1 = cvt_pk_bf16(p[10], p[11]);
            u32 y0 = cvt_pk_bf16(p[12], p[13]);
            u32 y1 = cvt_pk_bf16(p[14], p[15]);
            permswap32(x0, y0);
            permswap32(x1, y1);
            pb1.u[0] = x0; pb1.u[1] = x1; pb1.u[2] = y0; pb1.u[3] = y1;
        }
        o = __builtin_amdgcn_mfma_f32_32x32x16_bf16(vf[0], pb0.v, o, 0, 0, 0);
        o = __builtin_amdgcn_mfma_f32_32x32x16_bf16(vf[1], pb1.v, o, 0, 0, 0);
    };

    for (int c0 = 0; c0 < nkb; c0 += 8) {
        if (c0) __syncthreads();
        const char* Ks = Kb + (size_t)(kb_begin + c0) * 4096;
        const char* Vs = Vb + (size_t)(kb_begin + c0) * 2048;
        #pragma unroll
        for (int i = 0; i < 4; ++i) {
            const int idx = i * 512 + tid;
            *reinterpret_cast<uint4*>(kl + idx * 16) =
                *reinterpret_cast<const uint4*>(Ks + idx * 16);
        }
        #pragma unroll
        for (int i = 0; i < 2; ++i) {
            const int idx = i * 512 + tid;
            *reinterpret_cast<uint4*>(vl + idx * 16) =
                *reinterpret_cast<const uint4*>(Vs + idx * 16);
        }
        __syncthreads();

        #pragma unroll 2
        for (int kb = 0; kb < 8; ++kb) {
            bf16x8 kf[4], vf[2];
            const char* kbp = kl + kb * 4096 + lane * 16;
            #pragma unroll
            for (int c = 0; c < 4; ++c)
                kf[c] = *reinterpret_cast<const bf16x8*>(kbp + c * 1024);
            const char* vbp = vl + kb * 2048 + lane * 16;
            vf[0] = *reinterpret_cast<const bf16x8*>(vbp);
            vf[1] = *reinterpret_cast<const bf16x8*>(vbp + 1024);
            body(kf, vf);
        }
    }

    float lsum = lsumA + lsumB;
    lsum += __shfl_xor(lsum, 32);
    if (hi == 0) lP[(size_t)slice * n_map + tileT * 32 + ql] = lsum;
    __hip_bfloat16* ob = oP + ((size_t)slice * (n_map >> 5) + tileT) * 1024;
    #pragma unroll
    for (int r = 0; r < 16; ++r) {
        const int vr = (r & 3) + 8 * (r >> 2) + 4 * hi;
        ob[vr * 32 + ql] = __float2bfloat16(o[r]);
    }
}

// ----------------------------------------------------------- reduce_oP ----
// grid = ntiles*1024/(256*8); thread owns 8 consecutive agg elements.
// agg[T*1024 + t] = pself*gmT + sum_s oP[s][T][t]; uint4 loads, unroll 4.
__global__ __launch_bounds__(256) void reduce_oP(
    const __hip_bfloat16* __restrict__ oP, const float* __restrict__ pself,
    const float* __restrict__ gmT, float* __restrict__ agg,
    int n_map, int ks)
{
    const int gid = blockIdx.x * 256 + threadIdx.x;
    const int e0  = gid * 8;
    const int T   = e0 >> 10;
    const int t0  = e0 & 1023;
    const int v   = t0 >> 5;          // 8 elems stay within one v (8|t0)
    const int qq0 = t0 & 31;
    const int q0  = T * 32 + qq0;
    const int ntiles = n_map >> 5;

    float a[8];
    {
        const float4 ps0 = *reinterpret_cast<const float4*>(pself + q0);
        const float4 ps1 = *reinterpret_cast<const float4*>(pself + q0 + 4);
        const float4 g0  = *reinterpret_cast<const float4*>(gmT + (size_t)v * n_map + q0);
        const float4 g1  = *reinterpret_cast<const float4*>(gmT + (size_t)v * n_map + q0 + 4);
        a[0] = ps0.x * g0.x; a[1] = ps0.y * g0.y;
        a[2] = ps0.z * g0.z; a[3] = ps0.w * g0.w;
        a[4] = ps1.x * g1.x; a[5] = ps1.y * g1.y;
        a[6] = ps1.z * g1.z; a[7] = ps1.w * g1.w;
    }
    const __hip_bfloat16* ob = oP + (size_t)T * 1024 + t0;
    const size_t sstride = (size_t)ntiles * 1024;
    #pragma unroll 4
    for (int s = 0; s < ks; ++s) {
        const uint4 u = *reinterpret_cast<const uint4*>(ob + s * sstride);
        a[0] += __uint_as_float(u.x << 16);
        a[1] += __uint_as_float(u.x & 0xffff0000u);
        a[2] += __uint_as_float(u.y << 16);
        a[3] += __uint_as_float(u.y & 0xffff0000u);
        a[4] += __uint_as_float(u.z << 16);
        a[5] += __uint_as_float(u.z & 0xffff0000u);
        a[6] += __uint_as_float(u.w << 16);
        a[7] += __uint_as_float(u.w & 0xffff0000u);
    }
    float4* dst = reinterpret_cast<float4*>(agg + e0);
    dst[0] = make_float4(a[0], a[1], a[2], a[3]);
    dst[1] = make_float4(a[4], a[5], a[6], a[7]);
}

// ------------------------------------------------------------- epilogue ---
// grid = ntiles; 256 thr = 4 waves. Parallel lP reduce, LDS-staged agg,
// Wo matmul + residual + LayerNorm.
__global__ __launch_bounds__(256) void epilogue(
    const float* __restrict__ agg, const float* __restrict__ lP,
    const float* __restrict__ pself, const float* __restrict__ map_code,
    const float* __restrict__ Wo, const float* __restrict__ bo,
    const float* __restrict__ gamma, const float* __restrict__ beta,
    float* __restrict__ out, int n_map, int ks)
{
    const int tid  = threadIdx.x;
    const int w    = tid >> 6;
    const int lane = tid & 63;
    const int T    = blockIdx.x;
    const int q0   = T * 32;

    __shared__ float aggT[32][33];
    __shared__ float lsumL[8][32];
    __shared__ float invS[32];

    // parallel lP reduction: group g = tid>>5 handles slices g, g+8, ...
    {
        const int g  = tid >> 5;
        const int qq = tid & 31;
        float part = 0.0f;
        for (int s = g; s < ks; s += 8)
            part += lP[(size_t)s * n_map + q0 + qq];
        lsumL[g][qq] = part;
    }
    // stage agg into LDS (coalesced float4)
    {
        const float4 f4 = reinterpret_cast<const float4*>(agg + (size_t)T * 1024)[tid];
        const int v  = tid >> 3;
        const int qq = (tid & 7) * 4;
        aggT[v][qq + 0] = f4.x; aggT[v][qq + 1] = f4.y;
        aggT[v][qq + 2] = f4.z; aggT[v][qq + 3] = f4.w;
    }
    __syncthreads();
    if (tid < 32) {
        float l = pself[q0 + tid];
        #pragma unroll
        for (int g = 0; g < 8; ++g) l += lsumL[g][tid];
        invS[tid] = 1.0f / l;
    }
    __syncthreads();

    float wo[32];
    #pragma unroll
    for (int vv = 0; vv < 32; ++vv) wo[vv] = Wo[vv * 64 + lane];
    const float bo_e = bo[lane], ga = gamma[lane], be = beta[lane];

    #pragma unroll
    for (int i = 0; i < 8; ++i) {
        const int qq = w * 8 + i;
        float dot = 0.0f;
        #pragma unroll
        for (int vv = 0; vv < 32; ++vv)
            dot = fmaf(aggT[vv][qq], wo[vv], dot); // LDS broadcast reads
        float acc = dot * invS[qq] + bo_e + map_code[(size_t)(q0 + qq) * 64 + lane];
        float mu = acc;
        #pragma unroll
        for (int off = 32; off; off >>= 1) mu += __shfl_xor(mu, off);
        mu *= (1.0f / 64.0f);
        const float dc = acc - mu;
        float var = dc * dc;
        #pragma unroll
        for (int off = 32; off; off >>= 1) var += __shfl_xor(var, off);
        var *= (1.0f / 64.0f);
        out[(size_t)(q0 + qq) * 64 + lane] =
            dc * rsqrtf(var + 1e-6f) * ga + be;
    }
}

// -------------------------------------------------------------- launch ----
extern "C" void kernel_launch(void* const* d_in, const int* in_sizes, int n_in,
                              void* d_out, int out_size, void* d_ws, size_t ws_size,
                              hipStream_t stream) {
    const float* map_code = (const float*)d_in[0];
    const float* obs_code = (const float*)d_in[1];
    const float* Wq  = (const float*)d_in[2];
    const float* Wk  = (const float*)d_in[3];
    const float* Wv  = (const float*)d_in[4];
    const float* Wo  = (const float*)d_in[5];
    const float* bo  = (const float*)d_in[6];
    const float* gam = (const float*)d_in[7];
    const float* bet = (const float*)d_in[8];
    const int n_map = in_sizes[0] / 64;   // 16384
    const int n_obs = in_sizes[1] / 64;   // 8192
    const int ntiles = n_map / 32;        // 512

    char* ws = (char*)d_ws;
    __hip_bfloat16* qbf = (__hip_bfloat16*)ws; ws += (size_t)n_map * 64 * 2;
    __hip_bfloat16* Kp  = (__hip_bfloat16*)ws; ws += (size_t)n_obs * 64 * 2;
    __hip_bfloat16* Vp  = (__hip_bfloat16*)ws; ws += (size_t)n_obs * 32 * 2;
    float* pself        = (float*)ws;          ws += (size_t)n_map * 4;
    float* gmT          = (float*)ws;          ws += (size_t)n_map * 32 * 4;
    float* agg          = (float*)ws;          ws += (size_t)ntiles * 1024 * 4;
    const size_t base   = (size_t)(ws - (char*)d_ws);
    // per-slice partial cost: oP (n_map*32 bf16) + lP (n_map f32)
    const size_t per_slice = (size_t)n_map * 32 * 2 + (size_t)n_map * 4;
    int kslog = 5;   // ks=32 -> slice = 256 keys = 48KB (whole-slice LDS)
    while (kslog > 0 && base + ((size_t)1 << kslog) * per_slice > ws_size)
        --kslog;
    const int ks = 1 << kslog;
    __hip_bfloat16* oP = (__hip_bfloat16*)ws; ws += (size_t)ks * n_map * 32 * 2;
    float* lP = (float*)ws;  // ks * n_map * 4

    const int total = n_map + n_obs;
    prep_kernel<<<(total + 31) / 32, 256, 0, stream>>>(
        map_code, obs_code, Wq, Wk, Wv, qbf, Kp, Vp, pself, gmT,
        n_map, n_obs);
    attn_partial<<<(n_map / 256) * ks, 64 * WAVES, 0, stream>>>(
        qbf, Kp, Vp, oP, lP, n_obs, n_map, kslog);
    reduce_oP<<<(ntiles * 1024) / (256 * 8), 256, 0, stream>>>(
        oP, pself, gmT, agg, n_map, ks);
    epilogue<<<ntiles, 256, 0, stream>>>(
        agg, lP, pself, map_code, Wo, bo, gam, bet,
        (float*)d_out, n_map, ks);
}